// Round 12
// baseline (615.673 us; speedup 1.0000x reference)
//
#include <hip/hip_runtime.h>

typedef _Float16 half8 __attribute__((ext_vector_type(8)));
typedef float float4v __attribute__((ext_vector_type(4)));

// ---------------------------------------------------------------- front (batched over z)

// fused conv1x1+prelu for embed (64 ch, Wa) and match (32 ch, W1); x read once per
// co-chunk. grid (36, 6, B): chunks 0-3 -> embed co 0..63, chunks 4-5 -> match co 0..31.
__global__ __launch_bounds__(256) void conv_embed_match(
    const float* __restrict__ x, const float* __restrict__ Wa, const float* __restrict__ ba,
    const float* __restrict__ aa, const float* __restrict__ W1, const float* __restrict__ b1,
    const float* __restrict__ a1, float* __restrict__ embed2, float* __restrict__ match2) {
    int b = blockIdx.z;
    const float* xb = x + (size_t)b * 64 * 9216;
    int p = blockIdx.x * 256 + threadIdx.x;  // 9216 pixels
    int chunk = blockIdx.y;
    float xin[64];
#pragma unroll
    for (int ci = 0; ci < 64; ++ci) xin[ci] = xb[ci * 9216 + p];
    bool isE = chunk < 4;
    int co0 = (isE ? chunk : chunk - 4) * 16;
    const float* W = isE ? Wa : W1;
    const float* bb = isE ? ba : b1;
    float alpha = (isE ? aa : a1)[0];
    float* dst = isE ? (embed2 + (size_t)b * 64 * 9216) : (match2 + (size_t)b * 32 * 9216);
#pragma unroll
    for (int c = 0; c < 16; ++c) {
        int co = co0 + c;
        float s = bb[co];
#pragma unroll
        for (int ci = 0; ci < 64; ++ci) s += W[co * 64 + ci] * xin[ci];
        dst[co * 9216 + p] = s >= 0.f ? s : alpha * s;
    }
}

// ref conv with inline 2x2 mean pool. grid (9, 2, B).
__global__ __launch_bounds__(256) void conv_ref_pooled(
    const float* __restrict__ x, const float* __restrict__ W2, const float* __restrict__ b2,
    const float* __restrict__ a2, float* __restrict__ refb2) {
    int b = blockIdx.z;
    const float* xb = x + (size_t)b * 64 * 9216;
    int p = blockIdx.x * 256 + threadIdx.x;  // 0..2303
    int ph = p / 48, pw = p % 48;
    int co0 = blockIdx.y * 16;
    float xin[64];
#pragma unroll
    for (int ci = 0; ci < 64; ++ci) {
        const float* q = xb + ci * 9216 + ph * 2 * 96 + pw * 2;
        xin[ci] = 0.25f * (q[0] + q[1] + q[96] + q[97]);
    }
    float alpha = a2[0];
    float* dst = refb2 + (size_t)b * 32 * 2304;
#pragma unroll
    for (int c = 0; c < 16; ++c) {
        int co = co0 + c;
        float s = b2[co];
#pragma unroll
        for (int ci = 0; ci < 64; ++ci) s += W2[co * 64 + ci] * xin[ci];
        dst[co * 2304 + p] = s >= 0.f ? s : alpha * s;
    }
}

// ---------------------------------------------------------------- per-batch builds
// K for GEMM1 is padded 288 -> 320 (= 5*64) so the BK=64 GEMM applies; the pad
// region [288,320) is written with zeros every launch (ws is re-poisoned).

// xp[q][k] = match[c][qh+kh-1][qw+kw-1] (zero pad + K-pad), fp16, stride 320.
__global__ __launch_bounds__(256) void build_xp(const float* __restrict__ match,
                                                _Float16* __restrict__ xp) {
    int q = blockIdx.x * 4 + (threadIdx.x >> 6);
    int lane = threadIdx.x & 63;
    int qh = q / 96, qw = q % 96;
#pragma unroll
    for (int t = 0; t < 5; ++t) {
        int k = lane + t * 64;  // 0..319
        float v = 0.f;
        if (k < 288) {
            int c = k / 9, r = k % 9;
            int y = qh + r / 3 - 1, x = qw + r % 3 - 1;
            if (y >= 0 && y < 96 && x >= 0 && x < 96) v = match[c * 9216 + y * 96 + x];
        }
        xp[(size_t)q * 320 + k] = (_Float16)v;
    }
}

// wn[l][k] = 10 * patch / max(||patch||, 1e-4), fp16, stride 320 (tail zero).
__global__ void build_wn(const float* __restrict__ ref, _Float16* __restrict__ wn) {
    int l = blockIdx.x;  // 2304
    int oh = l / 48, ow = l % 48;
    int lane = threadIdx.x;  // 64
    float vals[5];
    float ss = 0.f;
#pragma unroll
    for (int t = 0; t < 5; ++t) {
        int i = lane + t * 64;
        float v = 0.f;
        if (i < 288) {
            int c = i / 9, r = i % 9, kh = r / 3, kw = r % 3;
            int y = oh + kh - 1, x = ow + kw - 1;
            v = (y >= 0 && y < 48 && x >= 0 && x < 48) ? ref[c * 2304 + y * 48 + x] : 0.f;
        }
        vals[t] = v;
        ss += v * v;
    }
#pragma unroll
    for (int d = 32; d; d >>= 1) ss += __shfl_xor(ss, d);
    float norm = sqrtf(ss);
    norm = norm < 1e-4f ? 1e-4f : norm;
    float inv = 10.f / norm;  // fold SOFTMAX_SCALE here
#pragma unroll
    for (int t = 0; t < 5; ++t) {
        int i = lane + t * 64;
        wn[(size_t)l * 320 + i] = (_Float16)(i < 288 ? vals[t] * inv : 0.f);
    }
}

// Wt[row=(o*36+i*6+j)][l=(lh*48+lw)] = embed[o][2lh+i-2][2lw+j-2] (zero pad), fp16
__global__ void build_Wt(const float* __restrict__ embed, _Float16* __restrict__ Wt) {
    int idx = blockIdx.x * 256 + threadIdx.x;
    if (idx >= 2304 * 2304) return;
    int row = idx / 2304, l = idx % 2304;
    int o = row / 36, rem = row % 36, i = rem / 6, j = rem % 6;
    int lh = l / 48, lw = l % 48;
    int y = 2 * lh + i - 2, x = 2 * lw + j - 2;
    float v = (y >= 0 && y < 96 && x >= 0 && x < 96) ? embed[o * 9216 + y * 96 + x] : 0.f;
    Wt[idx] = (_Float16)v;
}

// row softmax over l=2304 per q, fp16 logits in, fp16 normalized weights out
__global__ __launch_bounds__(256) void softmax_rows(const _Float16* __restrict__ S16,
                                                    _Float16* __restrict__ yi) {
    int q = blockIdx.x;
    const _Float16* row = S16 + (size_t)q * 2304;
    int tid = threadIdx.x;
    float v[9];
    float m = -1e30f;
#pragma unroll
    for (int t = 0; t < 9; ++t) {
        v[t] = (float)row[tid + t * 256];
        m = fmaxf(m, v[t]);
    }
    __shared__ float red[8];
#pragma unroll
    for (int d = 32; d; d >>= 1) m = fmaxf(m, __shfl_xor(m, d));
    if ((tid & 63) == 0) red[tid >> 6] = m;
    __syncthreads();
    m = fmaxf(fmaxf(red[0], red[1]), fmaxf(red[2], red[3]));
    float s = 0.f;
#pragma unroll
    for (int t = 0; t < 9; ++t) {
        v[t] = expf(v[t] - m);
        s += v[t];
    }
#pragma unroll
    for (int d = 32; d; d >>= 1) s += __shfl_xor(s, d);
    __syncthreads();
    if ((tid & 63) == 0) red[(tid >> 6) + 4] = s;
    __syncthreads();
    s = red[4] + red[5] + red[6] + red[7];
    float inv = 1.f / s;
    _Float16* orow = yi + (size_t)q * 2304;
#pragma unroll
    for (int t = 0; t < 9; ++t) orow[tid + t * 256] = (_Float16)(v[t] * inv);
}

// ---------------------------------------------------------------- MFMA GEMM (BK=64)
// C[M][N] = sum_k A[M][K] * B[N][K]  (K-contiguous fp16, K%64==0), fp32 accum.
// MODE 1: fp16 store.  MODE 2: rows<64 only, fp32 (acc+bias[row])/6.
// MSWAP: m0 from blockIdx.x (M-fastest dispatch → A persists in L2 when A is the
// larger reused operand; used for GEMM2 where A=Wt 10.6 MB, B=yi 42.5 MB).
// LDS rows 128 B = 8 x 16B slots, phys slot = src ^ (row&7): 2 lanes/bank (free).
template <int MODE, int MSWAP>
__global__ __launch_bounds__(256) void gemm_bk64(const _Float16* __restrict__ A,
                                                 const _Float16* __restrict__ B,
                                                 int M, int N, int K,
                                                 void* __restrict__ outv,
                                                 const float* __restrict__ bias) {
    __shared__ _Float16 As[128 * 64];
    __shared__ _Float16 Bs[128 * 64];
    int tid = threadIdx.x;
    int wave = tid >> 6, lane = tid & 63;
    int wm = wave >> 1, wn_ = wave & 1;  // 2x2 wave grid, 64x64 per wave
    int quad = lane >> 4, mrow = lane & 15;
    int m0 = (MSWAP ? blockIdx.x : blockIdx.y) * 128;
    int n0 = (MSWAP ? blockIdx.y : blockIdx.x) * 128;
    int crow = lane >> 3, cslot = lane & 7;  // staging: 8 rows x 8 slots per 1KB chunk
    float4v acc[4][4] = {};

    for (int k0 = 0; k0 < K; k0 += 64) {
#pragma unroll
        for (int r = 0; r < 4; ++r) {
            int c = wave * 4 + r;        // 0..15
            int row = c * 8 + crow;      // 0..127
            int ss = cslot ^ (row & 7);
            const _Float16* ga = A + (size_t)(m0 + row) * K + k0 + ss * 8;
            const _Float16* gb = B + (size_t)(n0 + row) * K + k0 + ss * 8;
            __builtin_amdgcn_global_load_lds(
                (const __attribute__((address_space(1))) unsigned int*)ga,
                (__attribute__((address_space(3))) unsigned int*)&As[c * 512], 16, 0, 0);
            __builtin_amdgcn_global_load_lds(
                (const __attribute__((address_space(1))) unsigned int*)gb,
                (__attribute__((address_space(3))) unsigned int*)&Bs[c * 512], 16, 0, 0);
        }
        __syncthreads();
        half8 af[2][4], bf[2][4];
#pragma unroll
        for (int d = 0; d < 2; ++d)
#pragma unroll
            for (int t = 0; t < 4; ++t) {
                int ar = wm * 64 + t * 16 + mrow;
                af[d][t] = *(const half8*)&As[ar * 64 + (((d * 4 + quad) ^ (ar & 7)) * 8)];
                int br = wn_ * 64 + t * 16 + mrow;
                bf[d][t] = *(const half8*)&Bs[br * 64 + (((d * 4 + quad) ^ (br & 7)) * 8)];
            }
#pragma unroll
        for (int d = 0; d < 2; ++d)
#pragma unroll
            for (int i = 0; i < 4; ++i)
#pragma unroll
                for (int j = 0; j < 4; ++j)
                    acc[i][j] =
                        __builtin_amdgcn_mfma_f32_16x16x32_f16(af[d][i], bf[d][j], acc[i][j], 0, 0, 0);
        __syncthreads();
    }

    // epilogue: D row m = quad*4+r (M dim), col n = lane&15 (N dim)
#pragma unroll
    for (int i = 0; i < 4; ++i)
#pragma unroll
        for (int j = 0; j < 4; ++j)
#pragma unroll
            for (int r = 0; r < 4; ++r) {
                int row = m0 + wm * 64 + i * 16 + quad * 4 + r;
                int col = n0 + wn_ * 64 + j * 16 + mrow;
                float v = acc[i][j][r];
                if (MODE == 1) {
                    ((_Float16*)outv)[(size_t)row * N + col] = (_Float16)v;
                } else {
                    if (row < 64)
                        ((float*)outv)[(size_t)row * N + col] = (v + bias[row]) * (1.f / 6.f);
                }
            }
}

// ---------------------------------------------------------------- tail

// gather (inverse of tconv scatter): yth[o][Y][X] = sum_{i==Y%2, j==X%2 (mod 2)}
//   Z[(o*36+i*6+j)][h*96+w],  h=(Y+2-i)/2, w=(X+2-j)/2 in range. fp16 in/out.
__global__ void gather_yt(const _Float16* __restrict__ Z, _Float16* __restrict__ yth) {
    int idx = blockIdx.x * 256 + threadIdx.x;
    if (idx >= 64 * 192 * 192) return;
    int o = idx / 36864, r = idx % 36864, Y = r / 192, X = r % 192;
    float s = 0.f;
    for (int i = Y & 1; i < 6; i += 2) {
        int h2 = Y + 2 - i;
        if (h2 < 0) continue;
        int h = h2 >> 1;
        if (h >= 96) continue;
        for (int j = X & 1; j < 6; j += 2) {
            int w2 = X + 2 - j;
            if (w2 < 0) continue;
            int w = w2 >> 1;
            if (w >= 96) continue;
            s += (float)Z[(size_t)(o * 36 + i * 6 + j) * 9216 + h * 96 + w];
        }
    }
    yth[idx] = (_Float16)s;
}

// im2col for the down conv (3x3, stride 2, pad 1), wave per q, lane-contiguous k.
__global__ __launch_bounds__(256) void build_P(const _Float16* __restrict__ yth,
                                               _Float16* __restrict__ P) {
    int q = blockIdx.x * 4 + (threadIdx.x >> 6);
    int lane = threadIdx.x & 63;
    int y = q / 96, x = q % 96;
#pragma unroll
    for (int t = 0; t < 9; ++t) {
        int k = lane + t * 64;
        int o = k / 9, r = k % 9;
        int Y = 2 * y - 1 + r / 3, X = 2 * x - 1 + r % 3;
        _Float16 v = (_Float16)0.f;
        if (Y >= 0 && Y < 192 && X >= 0 && X < 192) v = yth[o * 36864 + Y * 192 + X];
        P[(size_t)q * 576 + k] = v;
    }
}

// Wdh[op][k] fp16, rows 64..127 zero-padded
__global__ void build_Wdh(const float* __restrict__ Wd, _Float16* __restrict__ Wdh) {
    int idx = blockIdx.x * 256 + threadIdx.x;
    if (idx >= 128 * 576) return;
    int op = idx / 576;
    Wdh[idx] = (_Float16)(op < 64 ? Wd[idx] : 0.f);
}

// ---------------------------------------------------------------- launch

extern "C" void kernel_launch(void* const* d_in, const int* in_sizes, int n_in,
                              void* d_out, int out_size, void* d_ws, size_t ws_size,
                              hipStream_t stream) {
    const float* x = (const float*)d_in[0];
    const float* W1 = (const float*)d_in[1];
    const float* b1 = (const float*)d_in[2];
    const float* a1 = (const float*)d_in[3];
    const float* W2 = (const float*)d_in[4];
    const float* b2 = (const float*)d_in[5];
    const float* a2 = (const float*)d_in[6];
    const float* Wa = (const float*)d_in[7];
    const float* ba = (const float*)d_in[8];
    const float* aa = (const float*)d_in[9];
    const float* Wd = (const float*)d_in[10];
    const float* bd = (const float*)d_in[11];
    float* out = (float*)d_out;

    char* ws = (char*)d_ws;
    char* sreg = ws;                 ws += 84934656;  // region: S16 fp16 logits, then Z fp16
    _Float16* yi = (_Float16*)ws;    ws += 42467328;  // [9216][2304] fp16 softmax; P aliases
    _Float16* Wt = (_Float16*)ws;    ws += 10616832;  // [2304][2304] fp16; yth aliases
    _Float16* xp = (_Float16*)ws;    ws += 5898240;   // [9216][320] fp16 (K-padded)
    _Float16* wn = (_Float16*)ws;    ws += 1474560;   // [2304][320] fp16 (x10 folded, K-padded)
    float* embed2 = (float*)ws;      ws += 4718592;   // [2][64][96][96]
    float* match2 = (float*)ws;      ws += 2359296;   // [2][32][96][96]
    float* refb2 = (float*)ws;       ws += 589824;    // [2][32][48][48]
    _Float16* Wdh = (_Float16*)ws;   ws += 147456;    // [128][576] fp16 (rows 64+ zero)
    // region aliases (writer runs strictly after the last read of the aliased data)
    _Float16* S16 = (_Float16*)sreg;  // [9216][2304] fp16 logits (42.5 MB)
    _Float16* Z = (_Float16*)sreg;    // [2304][9216] fp16 — after softmax consumed S16
    _Float16* P = yi;                 // [9216][576] fp16 — after GEMM2 consumed yi
    _Float16* yth = Wt;               // [64][192][192] fp16 — after GEMM2 consumed Wt
    // total ~153.2 MB (< 158.6 MB proven in round 1)

    build_Wdh<<<288, 256, 0, stream>>>(Wd, Wdh);
    // batched front: both images at once (tiny grids otherwise underfill 256 CUs)
    conv_embed_match<<<dim3(36, 6, 2), 256, 0, stream>>>(x, Wa, ba, aa, W1, b1, a1, embed2, match2);
    conv_ref_pooled<<<dim3(9, 2, 2), 256, 0, stream>>>(x, W2, b2, a2, refb2);

    for (int b = 0; b < 2; ++b) {
        float* outb = out + (size_t)b * 64 * 9216;
        const float* embed = embed2 + (size_t)b * 64 * 9216;
        const float* match = match2 + (size_t)b * 32 * 9216;
        const float* refb = refb2 + (size_t)b * 32 * 2304;

        build_xp<<<2304, 256, 0, stream>>>(match, xp);
        build_wn<<<2304, 64, 0, stream>>>(refb, wn);
        build_Wt<<<20736, 256, 0, stream>>>(embed, Wt);

        // GEMM1 (BK=64, K padded to 320): S16[q][l] = <xp[q], wn[l]>
        gemm_bk64<1, 0><<<dim3(18, 72), 256, 0, stream>>>(xp, wn, 9216, 2304, 320, S16, nullptr);
        softmax_rows<<<9216, 256, 0, stream>>>(S16, yi);

        // GEMM2 (BK=64, M-fastest): Z[(oij)][q] = sum_l Wt[(oij)][l] * yi[q][l]
        gemm_bk64<1, 1><<<dim3(18, 72), 256, 0, stream>>>(Wt, yi, 2304, 9216, 2304, Z, nullptr);

        gather_yt<<<9216, 256, 0, stream>>>(Z, yth);
        build_P<<<2304, 256, 0, stream>>>(yth, P);
        // GEMM3 (BK=64): out[op][q] = (sum_k Wdh[op][k] P[q][k] + bd[op]) / 6
        gemm_bk64<2, 0><<<dim3(72, 1), 256, 0, stream>>>(Wdh, P, 128, 9216, 576, outb, bd);
    }
}

// Round 13
// 608.775 us; speedup vs baseline: 1.0113x; 1.0113x over previous
//
#include <hip/hip_runtime.h>

typedef _Float16 half8 __attribute__((ext_vector_type(8)));
typedef float float4v __attribute__((ext_vector_type(4)));

// ---------------------------------------------------------------- front (batched over z)

// fused conv1x1+prelu for embed (64 ch, Wa) and match (32 ch, W1); x read once per
// co-chunk. grid (36, 6, B): chunks 0-3 -> embed co 0..63, chunks 4-5 -> match co 0..31.
__global__ __launch_bounds__(256) void conv_embed_match(
    const float* __restrict__ x, const float* __restrict__ Wa, const float* __restrict__ ba,
    const float* __restrict__ aa, const float* __restrict__ W1, const float* __restrict__ b1,
    const float* __restrict__ a1, float* __restrict__ embed2, float* __restrict__ match2) {
    int b = blockIdx.z;
    const float* xb = x + (size_t)b * 64 * 9216;
    int p = blockIdx.x * 256 + threadIdx.x;  // 9216 pixels
    int chunk = blockIdx.y;
    float xin[64];
#pragma unroll
    for (int ci = 0; ci < 64; ++ci) xin[ci] = xb[ci * 9216 + p];
    bool isE = chunk < 4;
    int co0 = (isE ? chunk : chunk - 4) * 16;
    const float* W = isE ? Wa : W1;
    const float* bb = isE ? ba : b1;
    float alpha = (isE ? aa : a1)[0];
    float* dst = isE ? (embed2 + (size_t)b * 64 * 9216) : (match2 + (size_t)b * 32 * 9216);
#pragma unroll
    for (int c = 0; c < 16; ++c) {
        int co = co0 + c;
        float s = bb[co];
#pragma unroll
        for (int ci = 0; ci < 64; ++ci) s += W[co * 64 + ci] * xin[ci];
        dst[co * 9216 + p] = s >= 0.f ? s : alpha * s;
    }
}

// ref conv with inline 2x2 mean pool. grid (9, 2, B).
__global__ __launch_bounds__(256) void conv_ref_pooled(
    const float* __restrict__ x, const float* __restrict__ W2, const float* __restrict__ b2,
    const float* __restrict__ a2, float* __restrict__ refb2) {
    int b = blockIdx.z;
    const float* xb = x + (size_t)b * 64 * 9216;
    int p = blockIdx.x * 256 + threadIdx.x;  // 0..2303
    int ph = p / 48, pw = p % 48;
    int co0 = blockIdx.y * 16;
    float xin[64];
#pragma unroll
    for (int ci = 0; ci < 64; ++ci) {
        const float* q = xb + ci * 9216 + ph * 2 * 96 + pw * 2;
        xin[ci] = 0.25f * (q[0] + q[1] + q[96] + q[97]);
    }
    float alpha = a2[0];
    float* dst = refb2 + (size_t)b * 32 * 2304;
#pragma unroll
    for (int c = 0; c < 16; ++c) {
        int co = co0 + c;
        float s = b2[co];
#pragma unroll
        for (int ci = 0; ci < 64; ++ci) s += W2[co * 64 + ci] * xin[ci];
        dst[co * 2304 + p] = s >= 0.f ? s : alpha * s;
    }
}

// ---------------------------------------------------------------- per-batch builds
// K for GEMM1 is padded 288 -> 320 (= 5*64) so the BK=64 GEMM applies; the pad
// region [288,320) is written with zeros every launch (ws is re-poisoned).

// xp[q][k] = match[c][qh+kh-1][qw+kw-1] (zero pad + K-pad), fp16, stride 320.
__global__ __launch_bounds__(256) void build_xp(const float* __restrict__ match,
                                                _Float16* __restrict__ xp) {
    int q = blockIdx.x * 4 + (threadIdx.x >> 6);
    int lane = threadIdx.x & 63;
    int qh = q / 96, qw = q % 96;
#pragma unroll
    for (int t = 0; t < 5; ++t) {
        int k = lane + t * 64;  // 0..319
        float v = 0.f;
        if (k < 288) {
            int c = k / 9, r = k % 9;
            int y = qh + r / 3 - 1, x = qw + r % 3 - 1;
            if (y >= 0 && y < 96 && x >= 0 && x < 96) v = match[c * 9216 + y * 96 + x];
        }
        xp[(size_t)q * 320 + k] = (_Float16)v;
    }
}

// wn[l][k] = 10 * patch / max(||patch||, 1e-4), fp16, stride 320 (tail zero).
__global__ void build_wn(const float* __restrict__ ref, _Float16* __restrict__ wn) {
    int l = blockIdx.x;  // 2304
    int oh = l / 48, ow = l % 48;
    int lane = threadIdx.x;  // 64
    float vals[5];
    float ss = 0.f;
#pragma unroll
    for (int t = 0; t < 5; ++t) {
        int i = lane + t * 64;
        float v = 0.f;
        if (i < 288) {
            int c = i / 9, r = i % 9, kh = r / 3, kw = r % 3;
            int y = oh + kh - 1, x = ow + kw - 1;
            v = (y >= 0 && y < 48 && x >= 0 && x < 48) ? ref[c * 2304 + y * 48 + x] : 0.f;
        }
        vals[t] = v;
        ss += v * v;
    }
#pragma unroll
    for (int d = 32; d; d >>= 1) ss += __shfl_xor(ss, d);
    float norm = sqrtf(ss);
    norm = norm < 1e-4f ? 1e-4f : norm;
    float inv = 10.f / norm;  // fold SOFTMAX_SCALE here
#pragma unroll
    for (int t = 0; t < 5; ++t) {
        int i = lane + t * 64;
        wn[(size_t)l * 320 + i] = (_Float16)(i < 288 ? vals[t] * inv : 0.f);
    }
}

// Wt[row=(o*36+i*6+j)][l=(lh*48+lw)] = embed[o][2lh+i-2][2lw+j-2] (zero pad), fp16
__global__ void build_Wt(const float* __restrict__ embed, _Float16* __restrict__ Wt) {
    int idx = blockIdx.x * 256 + threadIdx.x;
    if (idx >= 2304 * 2304) return;
    int row = idx / 2304, l = idx % 2304;
    int o = row / 36, rem = row % 36, i = rem / 6, j = rem % 6;
    int lh = l / 48, lw = l % 48;
    int y = 2 * lh + i - 2, x = 2 * lw + j - 2;
    float v = (y >= 0 && y < 96 && x >= 0 && x < 96) ? embed[o * 9216 + y * 96 + x] : 0.f;
    Wt[idx] = (_Float16)v;
}

// row softmax over l=2304 per q, fp16 logits in, fp16 normalized weights out
__global__ __launch_bounds__(256) void softmax_rows(const _Float16* __restrict__ S16,
                                                    _Float16* __restrict__ yi) {
    int q = blockIdx.x;
    const _Float16* row = S16 + (size_t)q * 2304;
    int tid = threadIdx.x;
    float v[9];
    float m = -1e30f;
#pragma unroll
    for (int t = 0; t < 9; ++t) {
        v[t] = (float)row[tid + t * 256];
        m = fmaxf(m, v[t]);
    }
    __shared__ float red[8];
#pragma unroll
    for (int d = 32; d; d >>= 1) m = fmaxf(m, __shfl_xor(m, d));
    if ((tid & 63) == 0) red[tid >> 6] = m;
    __syncthreads();
    m = fmaxf(fmaxf(red[0], red[1]), fmaxf(red[2], red[3]));
    float s = 0.f;
#pragma unroll
    for (int t = 0; t < 9; ++t) {
        v[t] = expf(v[t] - m);
        s += v[t];
    }
#pragma unroll
    for (int d = 32; d; d >>= 1) s += __shfl_xor(s, d);
    __syncthreads();
    if ((tid & 63) == 0) red[(tid >> 6) + 4] = s;
    __syncthreads();
    s = red[4] + red[5] + red[6] + red[7];
    float inv = 1.f / s;
    _Float16* orow = yi + (size_t)q * 2304;
#pragma unroll
    for (int t = 0; t < 9; ++t) orow[tid + t * 256] = (_Float16)(v[t] * inv);
}

// ---------------------------------------------------------------- MFMA GEMM (BK=64)
// C[M][N] = sum_k A[M][K] * B[N][K]  (K-contiguous fp16, K%64==0), fp32 accum.
// MODE 1: fp16 store.  MODE 2: rows<64 only, fp32 (acc+bias[row])/6.
// N-fastest dispatch only (MSWAP measured: FETCH 108->231 MB, dur unchanged —
// GEMM2 is latency-plateau-bound, not memory-bound; per-XCD L2 is 4 MB so the
// 10.6 MB A operand can never persist. Keep the proven order.)
// LDS rows 128 B = 8 x 16B slots, phys slot = src ^ (row&7): 2 lanes/bank (free).
template <int MODE>
__global__ __launch_bounds__(256) void gemm_bk64(const _Float16* __restrict__ A,
                                                 const _Float16* __restrict__ B,
                                                 int M, int N, int K,
                                                 void* __restrict__ outv,
                                                 const float* __restrict__ bias) {
    __shared__ _Float16 As[128 * 64];
    __shared__ _Float16 Bs[128 * 64];
    int tid = threadIdx.x;
    int wave = tid >> 6, lane = tid & 63;
    int wm = wave >> 1, wn_ = wave & 1;  // 2x2 wave grid, 64x64 per wave
    int quad = lane >> 4, mrow = lane & 15;
    int m0 = blockIdx.y * 128, n0 = blockIdx.x * 128;
    int crow = lane >> 3, cslot = lane & 7;  // staging: 8 rows x 8 slots per 1KB chunk
    float4v acc[4][4] = {};

    for (int k0 = 0; k0 < K; k0 += 64) {
#pragma unroll
        for (int r = 0; r < 4; ++r) {
            int c = wave * 4 + r;        // 0..15
            int row = c * 8 + crow;      // 0..127
            int ss = cslot ^ (row & 7);
            const _Float16* ga = A + (size_t)(m0 + row) * K + k0 + ss * 8;
            const _Float16* gb = B + (size_t)(n0 + row) * K + k0 + ss * 8;
            __builtin_amdgcn_global_load_lds(
                (const __attribute__((address_space(1))) unsigned int*)ga,
                (__attribute__((address_space(3))) unsigned int*)&As[c * 512], 16, 0, 0);
            __builtin_amdgcn_global_load_lds(
                (const __attribute__((address_space(1))) unsigned int*)gb,
                (__attribute__((address_space(3))) unsigned int*)&Bs[c * 512], 16, 0, 0);
        }
        __syncthreads();
        half8 af[2][4], bf[2][4];
#pragma unroll
        for (int d = 0; d < 2; ++d)
#pragma unroll
            for (int t = 0; t < 4; ++t) {
                int ar = wm * 64 + t * 16 + mrow;
                af[d][t] = *(const half8*)&As[ar * 64 + (((d * 4 + quad) ^ (ar & 7)) * 8)];
                int br = wn_ * 64 + t * 16 + mrow;
                bf[d][t] = *(const half8*)&Bs[br * 64 + (((d * 4 + quad) ^ (br & 7)) * 8)];
            }
#pragma unroll
        for (int d = 0; d < 2; ++d)
#pragma unroll
            for (int i = 0; i < 4; ++i)
#pragma unroll
                for (int j = 0; j < 4; ++j)
                    acc[i][j] =
                        __builtin_amdgcn_mfma_f32_16x16x32_f16(af[d][i], bf[d][j], acc[i][j], 0, 0, 0);
        __syncthreads();
    }

    // epilogue: D row m = quad*4+r (M dim), col n = lane&15 (N dim)
#pragma unroll
    for (int i = 0; i < 4; ++i)
#pragma unroll
        for (int j = 0; j < 4; ++j)
#pragma unroll
            for (int r = 0; r < 4; ++r) {
                int row = m0 + wm * 64 + i * 16 + quad * 4 + r;
                int col = n0 + wn_ * 64 + j * 16 + mrow;
                float v = acc[i][j][r];
                if (MODE == 1) {
                    ((_Float16*)outv)[(size_t)row * N + col] = (_Float16)v;
                } else {
                    if (row < 64)
                        ((float*)outv)[(size_t)row * N + col] = (v + bias[row]) * (1.f / 6.f);
                }
            }
}

// ---------------------------------------------------------------- tail

// gather (inverse of tconv scatter): yth[o][Y][X] = sum_{i==Y%2, j==X%2 (mod 2)}
//   Z[(o*36+i*6+j)][h*96+w],  h=(Y+2-i)/2, w=(X+2-j)/2 in range. fp16 in/out.
__global__ void gather_yt(const _Float16* __restrict__ Z, _Float16* __restrict__ yth) {
    int idx = blockIdx.x * 256 + threadIdx.x;
    if (idx >= 64 * 192 * 192) return;
    int o = idx / 36864, r = idx % 36864, Y = r / 192, X = r % 192;
    float s = 0.f;
    for (int i = Y & 1; i < 6; i += 2) {
        int h2 = Y + 2 - i;
        if (h2 < 0) continue;
        int h = h2 >> 1;
        if (h >= 96) continue;
        for (int j = X & 1; j < 6; j += 2) {
            int w2 = X + 2 - j;
            if (w2 < 0) continue;
            int w = w2 >> 1;
            if (w >= 96) continue;
            s += (float)Z[(size_t)(o * 36 + i * 6 + j) * 9216 + h * 96 + w];
        }
    }
    yth[idx] = (_Float16)s;
}

// im2col for the down conv (3x3, stride 2, pad 1), wave per q, lane-contiguous k.
__global__ __launch_bounds__(256) void build_P(const _Float16* __restrict__ yth,
                                               _Float16* __restrict__ P) {
    int q = blockIdx.x * 4 + (threadIdx.x >> 6);
    int lane = threadIdx.x & 63;
    int y = q / 96, x = q % 96;
#pragma unroll
    for (int t = 0; t < 9; ++t) {
        int k = lane + t * 64;
        int o = k / 9, r = k % 9;
        int Y = 2 * y - 1 + r / 3, X = 2 * x - 1 + r % 3;
        _Float16 v = (_Float16)0.f;
        if (Y >= 0 && Y < 192 && X >= 0 && X < 192) v = yth[o * 36864 + Y * 192 + X];
        P[(size_t)q * 576 + k] = v;
    }
}

// Wdh[op][k] fp16, rows 64..127 zero-padded
__global__ void build_Wdh(const float* __restrict__ Wd, _Float16* __restrict__ Wdh) {
    int idx = blockIdx.x * 256 + threadIdx.x;
    if (idx >= 128 * 576) return;
    int op = idx / 576;
    Wdh[idx] = (_Float16)(op < 64 ? Wd[idx] : 0.f);
}

// ---------------------------------------------------------------- launch

extern "C" void kernel_launch(void* const* d_in, const int* in_sizes, int n_in,
                              void* d_out, int out_size, void* d_ws, size_t ws_size,
                              hipStream_t stream) {
    const float* x = (const float*)d_in[0];
    const float* W1 = (const float*)d_in[1];
    const float* b1 = (const float*)d_in[2];
    const float* a1 = (const float*)d_in[3];
    const float* W2 = (const float*)d_in[4];
    const float* b2 = (const float*)d_in[5];
    const float* a2 = (const float*)d_in[6];
    const float* Wa = (const float*)d_in[7];
    const float* ba = (const float*)d_in[8];
    const float* aa = (const float*)d_in[9];
    const float* Wd = (const float*)d_in[10];
    const float* bd = (const float*)d_in[11];
    float* out = (float*)d_out;

    char* ws = (char*)d_ws;
    char* sreg = ws;                 ws += 84934656;  // region: S16 fp16 logits, then Z fp16
    _Float16* yi = (_Float16*)ws;    ws += 42467328;  // [9216][2304] fp16 softmax; P aliases
    _Float16* Wt = (_Float16*)ws;    ws += 10616832;  // [2304][2304] fp16; yth aliases
    _Float16* xp = (_Float16*)ws;    ws += 5898240;   // [9216][320] fp16 (K-padded)
    _Float16* wn = (_Float16*)ws;    ws += 1474560;   // [2304][320] fp16 (x10 folded, K-padded)
    float* embed2 = (float*)ws;      ws += 4718592;   // [2][64][96][96]
    float* match2 = (float*)ws;      ws += 2359296;   // [2][32][96][96]
    float* refb2 = (float*)ws;       ws += 589824;    // [2][32][48][48]
    _Float16* Wdh = (_Float16*)ws;   ws += 147456;    // [128][576] fp16 (rows 64+ zero)
    // region aliases (writer runs strictly after the last read of the aliased data)
    _Float16* S16 = (_Float16*)sreg;  // [9216][2304] fp16 logits (42.5 MB)
    _Float16* Z = (_Float16*)sreg;    // [2304][9216] fp16 — after softmax consumed S16
    _Float16* P = yi;                 // [9216][576] fp16 — after GEMM2 consumed yi
    _Float16* yth = Wt;               // [64][192][192] fp16 — after GEMM2 consumed Wt
    // total ~153.2 MB (< 158.6 MB proven in round 1)

    build_Wdh<<<288, 256, 0, stream>>>(Wd, Wdh);
    // batched front: both images at once (tiny grids otherwise underfill 256 CUs)
    conv_embed_match<<<dim3(36, 6, 2), 256, 0, stream>>>(x, Wa, ba, aa, W1, b1, a1, embed2, match2);
    conv_ref_pooled<<<dim3(9, 2, 2), 256, 0, stream>>>(x, W2, b2, a2, refb2);

    for (int b = 0; b < 2; ++b) {
        float* outb = out + (size_t)b * 64 * 9216;
        const float* embed = embed2 + (size_t)b * 64 * 9216;
        const float* match = match2 + (size_t)b * 32 * 9216;
        const float* refb = refb2 + (size_t)b * 32 * 2304;

        build_xp<<<2304, 256, 0, stream>>>(match, xp);
        build_wn<<<2304, 64, 0, stream>>>(refb, wn);
        build_Wt<<<20736, 256, 0, stream>>>(embed, Wt);

        // GEMM1 (BK=64, K padded to 320): S16[q][l] = <xp[q], wn[l]>
        gemm_bk64<1><<<dim3(18, 72), 256, 0, stream>>>(xp, wn, 9216, 2304, 320, S16, nullptr);
        softmax_rows<<<9216, 256, 0, stream>>>(S16, yi);

        // GEMM2 (BK=64, N-fastest — proven order): Z[(oij)][q] = sum_l Wt[(oij)][l]*yi[q][l]
        gemm_bk64<1><<<dim3(72, 18), 256, 0, stream>>>(Wt, yi, 2304, 9216, 2304, Z, nullptr);

        gather_yt<<<9216, 256, 0, stream>>>(Z, yth);
        build_P<<<2304, 256, 0, stream>>>(yth, P);
        // GEMM3 (BK=64): out[op][q] = (sum_k Wdh[op][k] P[q][k] + bd[op]) / 6
        gemm_bk64<2><<<dim3(72, 1), 256, 0, stream>>>(Wdh, P, 128, 9216, 576, outb, bd);
    }
}